// Round 1
// baseline (471.758 us; speedup 1.0000x reference)
//
#include <hip/hip_runtime.h>

typedef unsigned short u16;
typedef __attribute__((ext_vector_type(4))) u16 u16x4;
typedef __attribute__((ext_vector_type(8))) __bf16 bf16x8;
typedef __attribute__((ext_vector_type(4))) float f32x4;

#define B_ 2
#define T_ 2048
#define DIM_ 2048
#define NH_ 16
#define HD_ 128

__device__ __forceinline__ u16 f2b(float f) {
  unsigned u = __builtin_bit_cast(unsigned, f);
  u += 0x7fffu + ((u >> 16) & 1u);
  return (u16)(u >> 16);
}
__device__ __forceinline__ float b2f(u16 h) {
  unsigned u = ((unsigned)h) << 16;
  return __builtin_bit_cast(float, u);
}

typedef __attribute__((address_space(1))) void gvoid_t;
typedef __attribute__((address_space(3))) void lvoid_t;
__device__ __forceinline__ void gload16(const void* g, void* l) {
  __builtin_amdgcn_global_load_lds((gvoid_t*)g, (lvoid_t*)l, 16, 0, 0);
}

// ---------------- fp32 -> bf16 conversion (x + 4 weights) ----------------
__global__ __launch_bounds__(256) void cvt_bf16(const float* x, const float* wq,
    const float* wk, const float* wv, const float* wo,
    u16* xb, u16* wqb, u16* wkb, u16* wvb, u16* wob) {
  int ten = blockIdx.y;
  const float* s; u16* d; int n4;
  if (ten == 0)      { s = x;  d = xb;  n4 = 2097152; }
  else if (ten == 1) { s = wq; d = wqb; n4 = 1048576; }
  else if (ten == 2) { s = wk; d = wkb; n4 = 1048576; }
  else if (ten == 3) { s = wv; d = wvb; n4 = 1048576; }
  else               { s = wo; d = wob; n4 = 1048576; }
  int i = blockIdx.x * 256 + threadIdx.x;
  if (i >= n4) return;
  float4 f = ((const float4*)s)[i];
  u16x4 o = { f2b(f.x), f2b(f.y), f2b(f.z), f2b(f.w) };
  ((u16x4*)d)[i] = o;
}

// ---------------- m97-style GEMM: C[M,N] = A[M,K] * B[N,K]^T ----------------
template <typename OutT>
__device__ __forceinline__ void gemm_bt_body(const u16* A, const u16* Bw, OutT* C) {
  constexpr int K = 2048, N = 2048;
  __shared__ u16 As[128 * 32];
  __shared__ u16 Bs[128 * 32];
  const int tid = threadIdx.x;
  const int w = tid >> 6, l = tid & 63, n = l & 15, quad = l >> 4;
  const int row0 = blockIdx.y * 128, col0 = blockIdx.x * 128;
  const int c = w * 64 + l;
  const int rA = c >> 2, kA = (c & 3) * 8;
  const u16* aP1 = A + (size_t)(row0 + rA) * K + kA;
  const u16* aP2 = A + (size_t)(row0 + 64 + rA) * K + kA;
  const u16* bP1 = Bw + (size_t)(col0 + rA) * K + kA;
  const u16* bP2 = Bw + (size_t)(col0 + 64 + rA) * K + kA;
  char* lA1 = (char*)As + (w * 64) * 16;
  char* lA2 = (char*)As + (256 + w * 64) * 16;
  char* lB1 = (char*)Bs + (w * 64) * 16;
  char* lB2 = (char*)Bs + (256 + w * 64) * 16;
  const int wr0 = (w >> 1) * 64, wc0 = (w & 1) * 64;
  f32x4 acc[4][4] = {};
  for (int kt = 0; kt < K; kt += 32) {
    gload16(aP1, lA1); gload16(aP2, lA2);
    gload16(bP1, lB1); gload16(bP2, lB2);
    aP1 += 32; aP2 += 32; bP1 += 32; bP2 += 32;
    __syncthreads();
    bf16x8 af[4], bfr[4];
#pragma unroll
    for (int mb = 0; mb < 4; ++mb)
      af[mb] = *(const bf16x8*)&As[(wr0 + mb * 16 + n) * 32 + quad * 8];
#pragma unroll
    for (int nb = 0; nb < 4; ++nb)
      bfr[nb] = *(const bf16x8*)&Bs[(wc0 + nb * 16 + n) * 32 + quad * 8];
#pragma unroll
    for (int mb = 0; mb < 4; ++mb)
#pragma unroll
      for (int nb = 0; nb < 4; ++nb)
        acc[mb][nb] = __builtin_amdgcn_mfma_f32_16x16x32_bf16(af[mb], bfr[nb], acc[mb][nb], 0, 0, 0);
    __syncthreads();
  }
#pragma unroll
  for (int mb = 0; mb < 4; ++mb)
#pragma unroll
    for (int nb = 0; nb < 4; ++nb)
#pragma unroll
      for (int r = 0; r < 4; ++r) {
        size_t idx = (size_t)(row0 + wr0 + mb * 16 + quad * 4 + r) * N + (col0 + wc0 + nb * 16 + n);
        float v = acc[mb][nb][r];
        if constexpr (sizeof(OutT) == 2) C[idx] = f2b(v); else C[idx] = v;
      }
}

__global__ __launch_bounds__(256) void gemm_qkv(const u16* A, const u16* w0, const u16* w1,
    const u16* w2, u16* c0, u16* c1, u16* c2) {
  const u16* Bw = (blockIdx.z == 0) ? w0 : (blockIdx.z == 1) ? w1 : w2;
  u16* C = (blockIdx.z == 0) ? c0 : (blockIdx.z == 1) ? c1 : c2;
  gemm_bt_body<u16>(A, Bw, C);
}
__global__ __launch_bounds__(256) void gemm_o(const u16* A, const u16* Bw, float* C) {
  gemm_bt_body<float>(A, Bw, C);
}

// ---------------- RoPE (partial: first 64 of each 128-dim head) ----------------
// Also folds softmax scale*log2(e) into Q.
__global__ __launch_bounds__(256) void rope_k(u16* Qb, u16* Kb) {
  int gid = blockIdx.x * 256 + threadIdx.x;   // 2M threads
  int j = gid & 31;
  int h = (gid >> 5) & 15;
  int row = gid >> 9;                          // 0..4095
  int t = row & (T_ - 1);
  bool isQ = (blockIdx.y == 0);
  u16* base = (isQ ? Qb : Kb) + (size_t)row * DIM_ + h * HD_;
  // inv_freq[j] = 10000^(-j/64); element j+32 uses inv_freq[j+32] = inv_freq[j]/100
  double f1 = exp2(-(double)j * 0.20762050593045951);  // log2(10000)/64
  double f2 = f1 * 0.01;
  const double INV2PI = 0.15915494309189535;
  double r1d = (double)t * f1 * INV2PI; r1d -= floor(r1d);
  double r2d = (double)t * f2 * INV2PI; r2d -= floor(r2d);
  float rv1 = (float)r1d, rv2 = (float)r2d;
  float c1 = __builtin_amdgcn_cosf(rv1), s1 = __builtin_amdgcn_sinf(rv1);
  float c2 = __builtin_amdgcn_cosf(rv2), s2 = __builtin_amdgcn_sinf(rv2);
  float x1 = b2f(base[j]), x2 = b2f(base[j + 32]);
  float scale = isQ ? 0.12751743342408354f : 1.0f;  // log2(e)/sqrt(128)
  base[j]      = f2b((x1 * c1 - x2 * s1) * scale);
  base[j + 32] = f2b((x2 * c2 + x1 * s2) * scale);
  if (isQ) {
    base[j + 64] = f2b(b2f(base[j + 64]) * scale);
    base[j + 96] = f2b(b2f(base[j + 96]) * scale);
  }
}

// ---------------- V transpose per batch: Vt[b][c][t] = V[b][t][c] ----------------
__global__ __launch_bounds__(256) void transpose_v(const u16* V, u16* Vt) {
  int b = blockIdx.z;
  int t0 = blockIdx.x * 64, c0 = blockIdx.y * 64;
  __shared__ u16 tile[64][72];
  int tid = threadIdx.x;
#pragma unroll
  for (int i = 0; i < 4; ++i) {
    int v = i * 256 + tid;
    int r = v >> 4, c4 = (v & 15) * 4;
    *(u16x4*)&tile[r][c4] = *(const u16x4*)(V + (size_t)(b * T_ + t0 + r) * DIM_ + c0 + c4);
  }
  __syncthreads();
#pragma unroll
  for (int i = 0; i < 4; ++i) {
    int v = i * 256 + tid;
    int d = v >> 4, t4 = (v & 15) * 4;
    u16x4 o = { tile[t4 + 0][d], tile[t4 + 1][d], tile[t4 + 2][d], tile[t4 + 3][d] };
    *(u16x4*)(Vt + (size_t)(b * DIM_ + c0 + d) * T_ + t0 + t4) = o;
  }
}

// ---------------- flash attention ----------------
__global__ __launch_bounds__(256, 1) void attn_k(const u16* Q, const u16* K, const u16* Vt, u16* Y) {
  const int qt = blockIdx.x, bh = blockIdx.y;
  const int b = bh >> 4, h = bh & 15;
  const int tid = threadIdx.x;
  const int w = tid >> 6, l = tid & 63, n = l & 15, quad = l >> 4;
  __shared__ u16 Ks[128 * 128];
  __shared__ u16 Vs[2][128 * 128];
  __shared__ u16 Ps[128 * 136];

  const u16* Qbase = Q + (size_t)(b * T_ + qt * 128) * DIM_ + h * HD_;
  const u16* Kbase = K + (size_t)(b * T_) * DIM_ + h * HD_;
  const u16* Vbase = Vt + (size_t)(b * DIM_ + h * HD_) * T_;

  const int wr0 = w * 32;
  bf16x8 qf[2][4];
#pragma unroll
  for (int mb = 0; mb < 2; ++mb)
#pragma unroll
    for (int s = 0; s < 4; ++s)
      qf[mb][s] = *(const bf16x8*)(Qbase + (size_t)(wr0 + mb * 16 + n) * DIM_ + s * 32 + quad * 8);

  auto stage = [&](const u16* rowbase, u16* lds) {
#pragma unroll
    for (int inst = 0; inst < 8; ++inst) {
      int ci = inst * 256 + w * 64 + l;
      int r = ci >> 4, cl = ci & 15;
      int cg = cl ^ (4 * (r & 3));
      gload16(rowbase + (size_t)r * 2048 + cg * 8, (char*)lds + (inst * 256 + w * 64) * 16);
    }
  };

  stage(Kbase, Ks);
  stage(Vbase, Vs[0]);
  f32x4 o[2][8] = {};
  float m_r[2][4], l_r[2][4];
#pragma unroll
  for (int mb = 0; mb < 2; ++mb)
#pragma unroll
    for (int r = 0; r < 4; ++r) { m_r[mb][r] = -__builtin_inff(); l_r[mb][r] = 0.f; }

  for (int it = 0; it < 16; ++it) {
    __syncthreads();  // K(it) in Ks, V(it) in Vs[it&1]
    if (it + 1 < 16) stage(Vbase + (it + 1) * 128, Vs[(it + 1) & 1]);

    // S = Q * K^T  (pre-scaled to log2 domain)
    f32x4 s_[2][8] = {};
#pragma unroll
    for (int ks = 0; ks < 4; ++ks) {
      bf16x8 kf[8];
#pragma unroll
      for (int nb = 0; nb < 8; ++nb)
        kf[nb] = *(const bf16x8*)&Ks[(nb * 16 + n) * 128 + (((ks * 4 + quad) ^ (4 * (n & 3))) * 8)];
#pragma unroll
      for (int mb = 0; mb < 2; ++mb)
#pragma unroll
        for (int nb = 0; nb < 8; ++nb)
          s_[mb][nb] = __builtin_amdgcn_mfma_f32_16x16x32_bf16(qf[mb][ks], kf[nb], s_[mb][nb], 0, 0, 0);
    }

    // online softmax (rows wave-local; 16-lane reductions)
#pragma unroll
    for (int mb = 0; mb < 2; ++mb)
#pragma unroll
      for (int r = 0; r < 4; ++r) {
        float mx = s_[mb][0][r];
#pragma unroll
        for (int nb = 1; nb < 8; ++nb) mx = fmaxf(mx, s_[mb][nb][r]);
        mx = fmaxf(mx, __shfl_xor(mx, 1, 64));
        mx = fmaxf(mx, __shfl_xor(mx, 2, 64));
        mx = fmaxf(mx, __shfl_xor(mx, 4, 64));
        mx = fmaxf(mx, __shfl_xor(mx, 8, 64));
        float mo = m_r[mb][r];
        float mn = fmaxf(mo, mx);
        float al = __builtin_amdgcn_exp2f(mo - mn);
        float rs = 0.f;
#pragma unroll
        for (int nb = 0; nb < 8; ++nb) {
          float p = __builtin_amdgcn_exp2f(s_[mb][nb][r] - mn);
          s_[mb][nb][r] = p;
          rs += p;
        }
        rs += __shfl_xor(rs, 1, 64);
        rs += __shfl_xor(rs, 2, 64);
        rs += __shfl_xor(rs, 4, 64);
        rs += __shfl_xor(rs, 8, 64);
        l_r[mb][r] = al * l_r[mb][r] + rs;
        m_r[mb][r] = mn;
#pragma unroll
        for (int nb = 0; nb < 8; ++nb) o[mb][nb][r] *= al;
      }

    // P -> LDS (padded stride 136)
#pragma unroll
    for (int mb = 0; mb < 2; ++mb)
#pragma unroll
      for (int nb = 0; nb < 8; ++nb)
#pragma unroll
        for (int r = 0; r < 4; ++r)
          Ps[(wr0 + mb * 16 + quad * 4 + r) * 136 + nb * 16 + n] = f2b(s_[mb][nb][r]);
    __syncthreads();  // Ps visible; Ks fully consumed
    if (it + 1 < 16) stage(Kbase + (size_t)((it + 1) * 128) * 2048, Ks);

    // O += P * V
    const u16* Vsc = Vs[it & 1];
#pragma unroll
    for (int ks = 0; ks < 4; ++ks) {
      bf16x8 pa[2];
#pragma unroll
      for (int mb = 0; mb < 2; ++mb)
        pa[mb] = *(const bf16x8*)&Ps[(wr0 + mb * 16 + n) * 136 + ks * 32 + quad * 8];
      bf16x8 vf[8];
#pragma unroll
      for (int nb = 0; nb < 8; ++nb)
        vf[nb] = *(const bf16x8*)&Vsc[(nb * 16 + n) * 128 + (((ks * 4 + quad) ^ (4 * (n & 3))) * 8)];
#pragma unroll
      for (int mb = 0; mb < 2; ++mb)
#pragma unroll
        for (int nb = 0; nb < 8; ++nb)
          o[mb][nb] = __builtin_amdgcn_mfma_f32_16x16x32_bf16(pa[mb], vf[nb], o[mb][nb], 0, 0, 0);
    }
  }

  u16* Ybase = Y + (size_t)(b * T_ + qt * 128) * DIM_ + h * HD_;
#pragma unroll
  for (int mb = 0; mb < 2; ++mb)
#pragma unroll
    for (int r = 0; r < 4; ++r) {
      float inv = 1.0f / l_r[mb][r];
#pragma unroll
      for (int nb = 0; nb < 8; ++nb)
        Ybase[(size_t)(wr0 + mb * 16 + quad * 4 + r) * DIM_ + nb * 16 + n] = f2b(o[mb][nb][r] * inv);
    }
}

extern "C" void kernel_launch(void* const* d_in, const int* in_sizes, int n_in,
                              void* d_out, int out_size, void* d_ws, size_t ws_size,
                              hipStream_t stream) {
  const float* x  = (const float*)d_in[0];
  const float* wq = (const float*)d_in[1];
  const float* wk = (const float*)d_in[2];
  const float* wv = (const float*)d_in[3];
  const float* wo = (const float*)d_in[4];

  u16* ws  = (u16*)d_ws;
  u16* xb  = ws;                   // 8388608
  u16* wqb = xb + 8388608;         // 4194304 each
  u16* wkb = wqb + 4194304;
  u16* wvb = wkb + 4194304;
  u16* wob = wvb + 4194304;
  u16* qb  = wob + 4194304;        // 8388608 each
  u16* kb  = qb + 8388608;
  u16* vb  = kb + 8388608;
  u16* vt  = vb + 8388608;
  u16* yb  = vt + 8388608;         // total 128 MiB

  cvt_bf16<<<dim3(8192, 5), 256, 0, stream>>>(x, wq, wk, wv, wo, xb, wqb, wkb, wvb, wob);
  gemm_qkv<<<dim3(16, 32, 3), 256, 0, stream>>>(xb, wqb, wkb, wvb, qb, kb, vb);
  rope_k<<<dim3(8192, 2), 256, 0, stream>>>(qb, kb);
  transpose_v<<<dim3(32, 32, 2), 256, 0, stream>>>(vb, vt);
  attn_k<<<dim3(16, 32), 256, 0, stream>>>(qb, kb, vt, yb);
  gemm_o<<<dim3(16, 32), 256, 0, stream>>>(yb, wob, (float*)d_out);
}

// Round 2
// 441.229 us; speedup vs baseline: 1.0692x; 1.0692x over previous
//
#include <hip/hip_runtime.h>

typedef unsigned short u16;
typedef __attribute__((ext_vector_type(4))) u16 u16x4;
typedef __attribute__((ext_vector_type(8))) __bf16 bf16x8;
typedef __attribute__((ext_vector_type(4))) float f32x4;

#define B_ 2
#define T_ 2048
#define DIM_ 2048
#define NH_ 16
#define HD_ 128

__device__ __forceinline__ u16 f2b(float f) {
  unsigned u = __builtin_bit_cast(unsigned, f);
  u += 0x7fffu + ((u >> 16) & 1u);
  return (u16)(u >> 16);
}
__device__ __forceinline__ float b2f(u16 h) {
  unsigned u = ((unsigned)h) << 16;
  return __builtin_bit_cast(float, u);
}
__device__ __forceinline__ unsigned pack2(float lo, float hi) {
  return (unsigned)f2b(lo) | ((unsigned)f2b(hi) << 16);
}

typedef __attribute__((address_space(1))) void gvoid_t;
typedef __attribute__((address_space(3))) void lvoid_t;
__device__ __forceinline__ void gload16(const void* g, void* l) {
  __builtin_amdgcn_global_load_lds((gvoid_t*)g, (lvoid_t*)l, 16, 0, 0);
}

// ---------------- fp32 -> bf16 conversion (x + 4 weights) ----------------
__global__ __launch_bounds__(256) void cvt_bf16(const float* x, const float* wq,
    const float* wk, const float* wv, const float* wo,
    u16* xb, u16* wqb, u16* wkb, u16* wvb, u16* wob) {
  int ten = blockIdx.y;
  const float* s; u16* d; int n4;
  if (ten == 0)      { s = x;  d = xb;  n4 = 2097152; }
  else if (ten == 1) { s = wq; d = wqb; n4 = 1048576; }
  else if (ten == 2) { s = wk; d = wkb; n4 = 1048576; }
  else if (ten == 3) { s = wv; d = wvb; n4 = 1048576; }
  else               { s = wo; d = wob; n4 = 1048576; }
  int i = blockIdx.x * 256 + threadIdx.x;
  if (i >= n4) return;
  float4 f = ((const float4*)s)[i];
  u16x4 o = { f2b(f.x), f2b(f.y), f2b(f.z), f2b(f.w) };
  ((u16x4*)d)[i] = o;
}

// ---------------- m97-style GEMM: C[M,N] = A[M,K] * B[N,K]^T ----------------
template <typename OutT>
__device__ __forceinline__ void gemm_bt_body(const u16* A, const u16* Bw, OutT* C) {
  constexpr int K = 2048, N = 2048;
  __shared__ u16 As[128 * 32];
  __shared__ u16 Bs[128 * 32];
  const int tid = threadIdx.x;
  const int w = tid >> 6, l = tid & 63, n = l & 15, quad = l >> 4;
  const int row0 = blockIdx.y * 128, col0 = blockIdx.x * 128;
  const int c = w * 64 + l;
  const int rA = c >> 2, kA = (c & 3) * 8;
  const u16* aP1 = A + (size_t)(row0 + rA) * K + kA;
  const u16* aP2 = A + (size_t)(row0 + 64 + rA) * K + kA;
  const u16* bP1 = Bw + (size_t)(col0 + rA) * K + kA;
  const u16* bP2 = Bw + (size_t)(col0 + 64 + rA) * K + kA;
  char* lA1 = (char*)As + (w * 64) * 16;
  char* lA2 = (char*)As + (256 + w * 64) * 16;
  char* lB1 = (char*)Bs + (w * 64) * 16;
  char* lB2 = (char*)Bs + (256 + w * 64) * 16;
  const int wr0 = (w >> 1) * 64, wc0 = (w & 1) * 64;
  f32x4 acc[4][4] = {};
  for (int kt = 0; kt < K; kt += 32) {
    gload16(aP1, lA1); gload16(aP2, lA2);
    gload16(bP1, lB1); gload16(bP2, lB2);
    aP1 += 32; aP2 += 32; bP1 += 32; bP2 += 32;
    __syncthreads();
    bf16x8 af[4], bfr[4];
#pragma unroll
    for (int mb = 0; mb < 4; ++mb)
      af[mb] = *(const bf16x8*)&As[(wr0 + mb * 16 + n) * 32 + quad * 8];
#pragma unroll
    for (int nb = 0; nb < 4; ++nb)
      bfr[nb] = *(const bf16x8*)&Bs[(wc0 + nb * 16 + n) * 32 + quad * 8];
#pragma unroll
    for (int mb = 0; mb < 4; ++mb)
#pragma unroll
      for (int nb = 0; nb < 4; ++nb)
        acc[mb][nb] = __builtin_amdgcn_mfma_f32_16x16x32_bf16(af[mb], bfr[nb], acc[mb][nb], 0, 0, 0);
    __syncthreads();
  }
#pragma unroll
  for (int mb = 0; mb < 4; ++mb)
#pragma unroll
    for (int nb = 0; nb < 4; ++nb)
#pragma unroll
      for (int r = 0; r < 4; ++r) {
        size_t idx = (size_t)(row0 + wr0 + mb * 16 + quad * 4 + r) * N + (col0 + wc0 + nb * 16 + n);
        float v = acc[mb][nb][r];
        if constexpr (sizeof(OutT) == 2) C[idx] = f2b(v); else C[idx] = v;
      }
}

__global__ __launch_bounds__(256) void gemm_qkv(const u16* A, const u16* w0, const u16* w1,
    const u16* w2, u16* c0, u16* c1, u16* c2) {
  const u16* Bw = (blockIdx.z == 0) ? w0 : (blockIdx.z == 1) ? w1 : w2;
  u16* C = (blockIdx.z == 0) ? c0 : (blockIdx.z == 1) ? c1 : c2;
  gemm_bt_body<u16>(A, Bw, C);
}
__global__ __launch_bounds__(256) void gemm_o(const u16* A, const u16* Bw, float* C) {
  gemm_bt_body<float>(A, Bw, C);
}

// ---------------- RoPE (partial: first 64 of each 128-dim head) ----------------
// Also folds softmax scale*log2(e) into Q.
__global__ __launch_bounds__(256) void rope_k(u16* Qb, u16* Kb) {
  int gid = blockIdx.x * 256 + threadIdx.x;   // 2M threads
  int j = gid & 31;
  int h = (gid >> 5) & 15;
  int row = gid >> 9;                          // 0..4095
  int t = row & (T_ - 1);
  bool isQ = (blockIdx.y == 0);
  u16* base = (isQ ? Qb : Kb) + (size_t)row * DIM_ + h * HD_;
  double f1 = exp2(-(double)j * 0.20762050593045951);  // log2(10000)/64
  double f2 = f1 * 0.01;
  const double INV2PI = 0.15915494309189535;
  double r1d = (double)t * f1 * INV2PI; r1d -= floor(r1d);
  double r2d = (double)t * f2 * INV2PI; r2d -= floor(r2d);
  float rv1 = (float)r1d, rv2 = (float)r2d;
  float c1 = __builtin_amdgcn_cosf(rv1), s1 = __builtin_amdgcn_sinf(rv1);
  float c2 = __builtin_amdgcn_cosf(rv2), s2 = __builtin_amdgcn_sinf(rv2);
  float x1 = b2f(base[j]), x2 = b2f(base[j + 32]);
  float scale = isQ ? 0.12751743342408354f : 1.0f;  // log2(e)/sqrt(128)
  base[j]      = f2b((x1 * c1 - x2 * s1) * scale);
  base[j + 32] = f2b((x2 * c2 + x1 * s2) * scale);
  if (isQ) {
    base[j + 64] = f2b(b2f(base[j + 64]) * scale);
    base[j + 96] = f2b(b2f(base[j + 96]) * scale);
  }
}

// ---------------- V transpose per batch: Vt[b][c][t] = V[b][t][c] ----------------
__global__ __launch_bounds__(256) void transpose_v(const u16* V, u16* Vt) {
  int b = blockIdx.z;
  int t0 = blockIdx.x * 64, c0 = blockIdx.y * 64;
  __shared__ u16 tile[64][72];
  int tid = threadIdx.x;
#pragma unroll
  for (int i = 0; i < 4; ++i) {
    int v = i * 256 + tid;
    int r = v >> 4, c4 = (v & 15) * 4;
    *(u16x4*)&tile[r][c4] = *(const u16x4*)(V + (size_t)(b * T_ + t0 + r) * DIM_ + c0 + c4);
  }
  __syncthreads();
#pragma unroll
  for (int i = 0; i < 4; ++i) {
    int v = i * 256 + tid;
    int d = v >> 4, t4 = (v & 15) * 4;
    u16x4 o = { tile[t4 + 0][d], tile[t4 + 1][d], tile[t4 + 2][d], tile[t4 + 3][d] };
    *(u16x4*)(Vt + (size_t)(b * DIM_ + c0 + d) * T_ + t0 + t4) = o;
  }
}

// ---------------- flash attention (transposed: S^T = K Q^T, O^T = V^T P^T) -------
// LDS = 64 KiB (K + V single-buffered) -> 2 blocks/CU. P never touches LDS:
// S^T C-layout (q = lane&15) -> P^T B-frag via packed-bf16 ds_bpermute + cndmask.
__global__ __launch_bounds__(256, 2) void attn_k(const u16* Q, const u16* K, const u16* Vt, u16* Y) {
  const int qt = blockIdx.x, bh = blockIdx.y;
  const int b = bh >> 4, h = bh & 15;
  const int tid = threadIdx.x;
  const int w = tid >> 6, l = tid & 63, n = l & 15, quad = l >> 4;
  __shared__ u16 Ks[128 * 128];
  __shared__ u16 Vs[128 * 128];

  const u16* Qbase = Q + (size_t)(b * T_ + qt * 128 + w * 32) * DIM_ + h * HD_;
  const u16* Kbase = K + (size_t)(b * T_) * DIM_ + h * HD_;
  const u16* Vbase = Vt + (size_t)(b * DIM_ + h * HD_) * T_;

  // Q fragments (B-operand): q = qtile*16+n (wave-local), hd chunk ks*32+quad*8
  bf16x8 qf[2][4];
#pragma unroll
  for (int qtile = 0; qtile < 2; ++qtile)
#pragma unroll
    for (int ks = 0; ks < 4; ++ks)
      qf[qtile][ks] = *(const bf16x8*)(Qbase + (size_t)(qtile * 16 + n) * DIM_ + ks * 32 + quad * 8);

  auto stage = [&](const u16* rowbase, u16* lds) {
#pragma unroll
    for (int inst = 0; inst < 8; ++inst) {
      int ci = inst * 256 + w * 64 + l;
      int r = ci >> 4, cl = ci & 15;
      int cg = cl ^ (4 * (r & 3));
      gload16(rowbase + (size_t)r * 2048 + cg * 8, (char*)lds + (inst * 256 + w * 64) * 16);
    }
  };

  stage(Kbase, Ks);
  stage(Vbase, Vs);

  f32x4 o[2][8] = {};
  float m_r[2] = { -__builtin_inff(), -__builtin_inff() };
  float l_r[2] = { 0.f, 0.f };

  // bpermute byte-addresses: src lane = ((quad&1)*2 + sel)*16 + n
  const int shA = ((quad & 1) * 2) * 16 + n;     // sel=0
  const int shB = shA + 16;                      // sel=1
  const bool hiTile = (quad >= 2);

  for (int it = 0; it < 16; ++it) {
    __syncthreads();  // K(it), V(it) staged

    // --- S^T = K Q^T ---
    f32x4 st[2][8] = {};
#pragma unroll
    for (int ks = 0; ks < 4; ++ks) {
      bf16x8 kf[8];
#pragma unroll
      for (int mt = 0; mt < 8; ++mt)
        kf[mt] = *(const bf16x8*)&Ks[(mt * 16 + n) * 128 + (((ks * 4 + quad) ^ (4 * (n & 3))) * 8)];
#pragma unroll
      for (int qtile = 0; qtile < 2; ++qtile)
#pragma unroll
        for (int mt = 0; mt < 8; ++mt)
          st[qtile][mt] = __builtin_amdgcn_mfma_f32_16x16x32_bf16(kf[mt], qf[qtile][ks], st[qtile][mt], 0, 0, 0);
    }
    __syncthreads();  // Ks fully consumed
    if (it + 1 < 16) stage(Kbase + (size_t)((it + 1) * 128) * 2048, Ks);  // overlaps softmax+PV

    // --- online softmax (per lane: q = qtile*16+n; kcols = mt*16+quad*4+r) ---
    unsigned pk[2][8][2];
#pragma unroll
    for (int qtile = 0; qtile < 2; ++qtile) {
      float mx = -__builtin_inff();
#pragma unroll
      for (int mt = 0; mt < 8; ++mt)
#pragma unroll
        for (int r = 0; r < 4; ++r) mx = fmaxf(mx, st[qtile][mt][r]);
      mx = fmaxf(mx, __shfl_xor(mx, 16, 64));
      mx = fmaxf(mx, __shfl_xor(mx, 32, 64));
      float mo = m_r[qtile];
      float mn = fmaxf(mo, mx);
      float al = __builtin_amdgcn_exp2f(mo - mn);
      float rs = 0.f;
#pragma unroll
      for (int mt = 0; mt < 8; ++mt)
#pragma unroll
        for (int r = 0; r < 4; ++r) {
          float p = __builtin_amdgcn_exp2f(st[qtile][mt][r] - mn);
          st[qtile][mt][r] = p;
          rs += p;
        }
      rs += __shfl_xor(rs, 16, 64);
      rs += __shfl_xor(rs, 32, 64);
      l_r[qtile] = al * l_r[qtile] + rs;
      m_r[qtile] = mn;
#pragma unroll
      for (int mt = 0; mt < 8; ++mt) {
        pk[qtile][mt][0] = pack2(st[qtile][mt][0], st[qtile][mt][1]);
        pk[qtile][mt][1] = pack2(st[qtile][mt][2], st[qtile][mt][3]);
      }
#pragma unroll
      for (int mt = 0; mt < 8; ++mt)
#pragma unroll
        for (int r = 0; r < 4; ++r) o[qtile][mt][r] *= al;
    }

    // --- build P^T B-frags via cross-lane permute ---
    // frag(qtile,ks) reg jj: bf16 pair (kcol = ks*32+quad*8+2jj, +1), q = qtile*16+n
    typedef __attribute__((ext_vector_type(4))) unsigned uint4v;
    uint4v pT[2][4];
#pragma unroll
    for (int qtile = 0; qtile < 2; ++qtile)
#pragma unroll
      for (int ks = 0; ks < 4; ++ks) {
#pragma unroll
        for (int jj = 0; jj < 4; ++jj) {
          int src = (jj < 2) ? shA : shB;
          unsigned vA = __shfl((int)pk[qtile][ks * 2][jj & 1], src, 64);
          unsigned vB = __shfl((int)pk[qtile][ks * 2 + 1][jj & 1], src, 64);
          pT[qtile][ks][jj] = hiTile ? vB : vA;
        }
      }

    // --- O^T += V^T P^T ---
#pragma unroll
    for (int ks = 0; ks < 4; ++ks) {
      bf16x8 vf[8];
#pragma unroll
      for (int mt = 0; mt < 8; ++mt)
        vf[mt] = *(const bf16x8*)&Vs[(mt * 16 + n) * 128 + (((ks * 4 + quad) ^ (4 * (n & 3))) * 8)];
#pragma unroll
      for (int qtile = 0; qtile < 2; ++qtile) {
        bf16x8 pfrag = __builtin_bit_cast(bf16x8, pT[qtile][ks]);
#pragma unroll
        for (int mt = 0; mt < 8; ++mt)
          o[qtile][mt] = __builtin_amdgcn_mfma_f32_16x16x32_bf16(vf[mt], pfrag, o[qtile][mt], 0, 0, 0);
      }
    }
    __syncthreads();  // Vs fully consumed
    if (it + 1 < 16) stage(Vbase + (it + 1) * 128, Vs);
  }

  // --- epilogue: O^T -> Y[q][d]; quads of fixed n cover contiguous d ---
  u16* Ybase = Y + (size_t)(b * T_ + qt * 128 + w * 32) * DIM_ + h * HD_;
#pragma unroll
  for (int qtile = 0; qtile < 2; ++qtile) {
    float inv = 1.0f / l_r[qtile];
#pragma unroll
    for (int mt = 0; mt < 8; ++mt) {
      u16x4 ov = { f2b(o[qtile][mt][0] * inv), f2b(o[qtile][mt][1] * inv),
                   f2b(o[qtile][mt][2] * inv), f2b(o[qtile][mt][3] * inv) };
      *(u16x4*)(Ybase + (size_t)(qtile * 16 + n) * DIM_ + mt * 16 + quad * 4) = ov;
    }
  }
}

extern "C" void kernel_launch(void* const* d_in, const int* in_sizes, int n_in,
                              void* d_out, int out_size, void* d_ws, size_t ws_size,
                              hipStream_t stream) {
  const float* x  = (const float*)d_in[0];
  const float* wq = (const float*)d_in[1];
  const float* wk = (const float*)d_in[2];
  const float* wv = (const float*)d_in[3];
  const float* wo = (const float*)d_in[4];

  u16* ws  = (u16*)d_ws;
  u16* xb  = ws;                   // 8388608
  u16* wqb = xb + 8388608;         // 4194304 each
  u16* wkb = wqb + 4194304;
  u16* wvb = wkb + 4194304;
  u16* wob = wvb + 4194304;
  u16* qb  = wob + 4194304;        // 8388608 each
  u16* kb  = qb + 8388608;
  u16* vb  = kb + 8388608;
  u16* vt  = vb + 8388608;
  u16* yb  = vt + 8388608;         // total 128 MiB

  cvt_bf16<<<dim3(8192, 5), 256, 0, stream>>>(x, wq, wk, wv, wo, xb, wqb, wkb, wvb, wob);
  gemm_qkv<<<dim3(16, 32, 3), 256, 0, stream>>>(xb, wqb, wkb, wvb, qb, kb, vb);
  rope_k<<<dim3(8192, 2), 256, 0, stream>>>(qb, kb);
  transpose_v<<<dim3(32, 32, 2), 256, 0, stream>>>(vb, vt);
  attn_k<<<dim3(16, 32), 256, 0, stream>>>(qb, kb, vt, yb);
  gemm_o<<<dim3(16, 32), 256, 0, stream>>>(yb, wob, (float*)d_out);
}

// Round 3
// 419.853 us; speedup vs baseline: 1.1236x; 1.0509x over previous
//
#include <hip/hip_runtime.h>

typedef unsigned short u16;
typedef __attribute__((ext_vector_type(4))) u16 u16x4;
typedef __attribute__((ext_vector_type(8))) __bf16 bf16x8;
typedef __attribute__((ext_vector_type(4))) float f32x4;

#define B_ 2
#define T_ 2048
#define DIM_ 2048
#define NH_ 16
#define HD_ 128

__device__ __forceinline__ u16 f2b(float f) {
  unsigned u = __builtin_bit_cast(unsigned, f);
  u += 0x7fffu + ((u >> 16) & 1u);
  return (u16)(u >> 16);
}
__device__ __forceinline__ float b2f(u16 h) {
  unsigned u = ((unsigned)h) << 16;
  return __builtin_bit_cast(float, u);
}
__device__ __forceinline__ unsigned pack2(float lo, float hi) {
  return (unsigned)f2b(lo) | ((unsigned)f2b(hi) << 16);
}

typedef __attribute__((address_space(1))) void gvoid_t;
typedef __attribute__((address_space(3))) void lvoid_t;
__device__ __forceinline__ void gload16(const void* g, void* l) {
  __builtin_amdgcn_global_load_lds((gvoid_t*)g, (lvoid_t*)l, 16, 0, 0);
}

// ---------------- fp32 -> bf16 conversion (x + 4 weights) ----------------
__global__ __launch_bounds__(256) void cvt_bf16(const float* x, const float* wq,
    const float* wk, const float* wv, const float* wo,
    u16* xb, u16* wqb, u16* wkb, u16* wvb, u16* wob) {
  int ten = blockIdx.y;
  const float* s; u16* d; int n4;
  if (ten == 0)      { s = x;  d = xb;  n4 = 2097152; }
  else if (ten == 1) { s = wq; d = wqb; n4 = 1048576; }
  else if (ten == 2) { s = wk; d = wkb; n4 = 1048576; }
  else if (ten == 3) { s = wv; d = wvb; n4 = 1048576; }
  else               { s = wo; d = wob; n4 = 1048576; }
  int i = blockIdx.x * 256 + threadIdx.x;
  if (i >= n4) return;
  float4 f = ((const float4*)s)[i];
  u16x4 o = { f2b(f.x), f2b(f.y), f2b(f.z), f2b(f.w) };
  ((u16x4*)d)[i] = o;
}

// ---------------- m97-style GEMM: C[M,N] = A[M,K] * B[N,K]^T ----------------
template <typename OutT>
__device__ __forceinline__ void gemm_bt_body(const u16* A, const u16* Bw, OutT* C) {
  constexpr int K = 2048, N = 2048;
  __shared__ u16 As[128 * 32];
  __shared__ u16 Bs[128 * 32];
  const int tid = threadIdx.x;
  const int w = tid >> 6, l = tid & 63, n = l & 15, quad = l >> 4;
  const int row0 = blockIdx.y * 128, col0 = blockIdx.x * 128;
  const int c = w * 64 + l;
  const int rA = c >> 2, kA = (c & 3) * 8;
  const u16* aP1 = A + (size_t)(row0 + rA) * K + kA;
  const u16* aP2 = A + (size_t)(row0 + 64 + rA) * K + kA;
  const u16* bP1 = Bw + (size_t)(col0 + rA) * K + kA;
  const u16* bP2 = Bw + (size_t)(col0 + 64 + rA) * K + kA;
  char* lA1 = (char*)As + (w * 64) * 16;
  char* lA2 = (char*)As + (256 + w * 64) * 16;
  char* lB1 = (char*)Bs + (w * 64) * 16;
  char* lB2 = (char*)Bs + (256 + w * 64) * 16;
  const int wr0 = (w >> 1) * 64, wc0 = (w & 1) * 64;
  f32x4 acc[4][4] = {};
  for (int kt = 0; kt < K; kt += 32) {
    gload16(aP1, lA1); gload16(aP2, lA2);
    gload16(bP1, lB1); gload16(bP2, lB2);
    aP1 += 32; aP2 += 32; bP1 += 32; bP2 += 32;
    __syncthreads();
    bf16x8 af[4], bfr[4];
#pragma unroll
    for (int mb = 0; mb < 4; ++mb)
      af[mb] = *(const bf16x8*)&As[(wr0 + mb * 16 + n) * 32 + quad * 8];
#pragma unroll
    for (int nb = 0; nb < 4; ++nb)
      bfr[nb] = *(const bf16x8*)&Bs[(wc0 + nb * 16 + n) * 32 + quad * 8];
#pragma unroll
    for (int mb = 0; mb < 4; ++mb)
#pragma unroll
      for (int nb = 0; nb < 4; ++nb)
        acc[mb][nb] = __builtin_amdgcn_mfma_f32_16x16x32_bf16(af[mb], bfr[nb], acc[mb][nb], 0, 0, 0);
    __syncthreads();
  }
#pragma unroll
  for (int mb = 0; mb < 4; ++mb)
#pragma unroll
    for (int nb = 0; nb < 4; ++nb)
#pragma unroll
      for (int r = 0; r < 4; ++r) {
        size_t idx = (size_t)(row0 + wr0 + mb * 16 + quad * 4 + r) * N + (col0 + wc0 + nb * 16 + n);
        float v = acc[mb][nb][r];
        if constexpr (sizeof(OutT) == 2) C[idx] = f2b(v); else C[idx] = v;
      }
}

__global__ __launch_bounds__(256) void gemm_qkv(const u16* A, const u16* w0, const u16* w1,
    const u16* w2, u16* c0, u16* c1, u16* c2) {
  const u16* Bw = (blockIdx.z == 0) ? w0 : (blockIdx.z == 1) ? w1 : w2;
  u16* C = (blockIdx.z == 0) ? c0 : (blockIdx.z == 1) ? c1 : c2;
  gemm_bt_body<u16>(A, Bw, C);
}
__global__ __launch_bounds__(256) void gemm_o(const u16* A, const u16* Bw, float* C) {
  gemm_bt_body<float>(A, Bw, C);
}

// ---------------- RoPE (partial: first 64 of each 128-dim head) ----------------
__global__ __launch_bounds__(256) void rope_k(u16* Qb, u16* Kb) {
  int gid = blockIdx.x * 256 + threadIdx.x;   // 2M threads
  int j = gid & 31;
  int h = (gid >> 5) & 15;
  int row = gid >> 9;                          // 0..4095
  int t = row & (T_ - 1);
  bool isQ = (blockIdx.y == 0);
  u16* base = (isQ ? Qb : Kb) + (size_t)row * DIM_ + h * HD_;
  double f1 = exp2(-(double)j * 0.20762050593045951);  // log2(10000)/64
  double f2 = f1 * 0.01;
  const double INV2PI = 0.15915494309189535;
  double r1d = (double)t * f1 * INV2PI; r1d -= floor(r1d);
  double r2d = (double)t * f2 * INV2PI; r2d -= floor(r2d);
  float rv1 = (float)r1d, rv2 = (float)r2d;
  float c1 = __builtin_amdgcn_cosf(rv1), s1 = __builtin_amdgcn_sinf(rv1);
  float c2 = __builtin_amdgcn_cosf(rv2), s2 = __builtin_amdgcn_sinf(rv2);
  float x1 = b2f(base[j]), x2 = b2f(base[j + 32]);
  float scale = isQ ? 0.12751743342408354f : 1.0f;  // log2(e)/sqrt(128)
  base[j]      = f2b((x1 * c1 - x2 * s1) * scale);
  base[j + 32] = f2b((x2 * c2 + x1 * s2) * scale);
  if (isQ) {
    base[j + 64] = f2b(b2f(base[j + 64]) * scale);
    base[j + 96] = f2b(b2f(base[j + 96]) * scale);
  }
}

// ---------------- V transpose per batch: Vt[b][c][t] = V[b][t][c] ----------------
__global__ __launch_bounds__(256) void transpose_v(const u16* V, u16* Vt) {
  int b = blockIdx.z;
  int t0 = blockIdx.x * 64, c0 = blockIdx.y * 64;
  __shared__ u16 tile[64][72];
  int tid = threadIdx.x;
#pragma unroll
  for (int i = 0; i < 4; ++i) {
    int v = i * 256 + tid;
    int r = v >> 4, c4 = (v & 15) * 4;
    *(u16x4*)&tile[r][c4] = *(const u16x4*)(V + (size_t)(b * T_ + t0 + r) * DIM_ + c0 + c4);
  }
  __syncthreads();
#pragma unroll
  for (int i = 0; i < 4; ++i) {
    int v = i * 256 + tid;
    int d = v >> 4, t4 = (v & 15) * 4;
    u16x4 o = { tile[t4 + 0][d], tile[t4 + 1][d], tile[t4 + 2][d], tile[t4 + 3][d] };
    *(u16x4*)(Vt + (size_t)(b * DIM_ + c0 + d) * T_ + t0 + t4) = o;
  }
}

// ---------------- flash attention (transposed; BK=64; K,V double-buffered) ------
// One barrier per iteration: stage(it+1) issued right AFTER the barrier so the
// vmcnt drain at the NEXT barrier happens a full compute-iter later (no stall).
// LDS chunk swizzle c^(r&7): 8 consecutive lanes sweep all 8 bank groups.
__global__ __launch_bounds__(256, 2) void attn_k(const u16* Q, const u16* K, const u16* Vt, u16* Y) {
  const int qt = blockIdx.x, bh = blockIdx.y;
  const int b = bh >> 4, h = bh & 15;
  const int tid = threadIdx.x;
  const int w = tid >> 6, l = tid & 63, n = l & 15, quad = l >> 4;
  __shared__ u16 Ks[2][64 * 128];   // [k-row][hd]
  __shared__ u16 Vs[2][128 * 64];   // [d-row][t]

  const u16* Qbase = Q + (size_t)(b * T_ + qt * 128 + w * 32) * DIM_ + h * HD_;
  const u16* Kbase = K + (size_t)(b * T_) * DIM_ + h * HD_;
  const u16* Vbase = Vt + (size_t)(b * DIM_ + h * HD_) * T_;

  // Q fragments (B-operand), iter-invariant, register-resident
  bf16x8 qf[2][4];
#pragma unroll
  for (int qtile = 0; qtile < 2; ++qtile)
#pragma unroll
    for (int ks = 0; ks < 4; ++ks)
      qf[qtile][ks] = *(const bf16x8*)(Qbase + (size_t)(qtile * 16 + n) * DIM_ + ks * 32 + quad * 8);

  auto stageK = [&](int itn, u16* dst) {   // 64 rows x 128 hd (16 chunks/row)
#pragma unroll
    for (int inst = 0; inst < 4; ++inst) {
      int ci = inst * 256 + w * 64 + l;
      int r = ci >> 4, cl = ci & 15;
      int cg = cl ^ (r & 7);
      gload16(Kbase + (size_t)(itn * 64 + r) * DIM_ + cg * 8, (char*)dst + (inst * 256 + w * 64) * 16);
    }
  };
  auto stageV = [&](int itn, u16* dst) {   // 128 rows x 64 t (8 chunks/row)
#pragma unroll
    for (int inst = 0; inst < 4; ++inst) {
      int ci = inst * 256 + w * 64 + l;
      int r = ci >> 3, cl = ci & 7;
      int cg = cl ^ (r & 7);
      gload16(Vbase + (size_t)r * T_ + itn * 64 + cg * 8, (char*)dst + (inst * 256 + w * 64) * 16);
    }
  };

  f32x4 o[2][8] = {};
  float m_r[2] = { -__builtin_inff(), -__builtin_inff() };
  float l_r[2] = { 0.f, 0.f };

  const int shA = ((quad & 1) * 2) * 16 + n;
  const int shB = shA + 16;
  const bool hiTile = (quad >= 2);

  auto iter_body = [&](const u16* Kc, const u16* Vc, u16* Kn, u16* Vn, int itn) {
    __syncthreads();  // bufs for this iter ready; prev iter's reads done
    if (itn >= 0) { stageK(itn, Kn); stageV(itn, Vn); }

    // --- S^T = K Q^T ---
    f32x4 st[2][4] = {};
#pragma unroll
    for (int ks = 0; ks < 4; ++ks) {
      bf16x8 kf[4];
#pragma unroll
      for (int mt = 0; mt < 4; ++mt)
        kf[mt] = *(const bf16x8*)&Kc[(mt * 16 + n) * 128 + (((ks * 4 + quad) ^ (n & 7)) * 8)];
#pragma unroll
      for (int qtile = 0; qtile < 2; ++qtile)
#pragma unroll
        for (int mt = 0; mt < 4; ++mt)
          st[qtile][mt] = __builtin_amdgcn_mfma_f32_16x16x32_bf16(kf[mt], qf[qtile][ks], st[qtile][mt], 0, 0, 0);
    }

    // --- online softmax (q = qtile*16+n per lane; kcols = mt*16+quad*4+r) ---
    unsigned pk[2][4][2];
#pragma unroll
    for (int qtile = 0; qtile < 2; ++qtile) {
      float mx = -__builtin_inff();
#pragma unroll
      for (int mt = 0; mt < 4; ++mt)
#pragma unroll
        for (int r = 0; r < 4; ++r) mx = fmaxf(mx, st[qtile][mt][r]);
      mx = fmaxf(mx, __shfl_xor(mx, 16, 64));
      mx = fmaxf(mx, __shfl_xor(mx, 32, 64));
      float mo = m_r[qtile];
      float mn = fmaxf(mo, mx);
      float al = __builtin_amdgcn_exp2f(mo - mn);
      float rs = 0.f;
#pragma unroll
      for (int mt = 0; mt < 4; ++mt)
#pragma unroll
        for (int r = 0; r < 4; ++r) {
          float p = __builtin_amdgcn_exp2f(st[qtile][mt][r] - mn);
          st[qtile][mt][r] = p;
          rs += p;
        }
      rs += __shfl_xor(rs, 16, 64);
      rs += __shfl_xor(rs, 32, 64);
      l_r[qtile] = al * l_r[qtile] + rs;
      m_r[qtile] = mn;
#pragma unroll
      for (int mt = 0; mt < 4; ++mt) {
        pk[qtile][mt][0] = pack2(st[qtile][mt][0], st[qtile][mt][1]);
        pk[qtile][mt][1] = pack2(st[qtile][mt][2], st[qtile][mt][3]);
      }
#pragma unroll
      for (int mt = 0; mt < 8; ++mt)
#pragma unroll
        for (int r = 0; r < 4; ++r) o[qtile][mt][r] *= al;
    }

    // --- P^T B-frags via cross-lane permute (32 shuffles) ---
    typedef __attribute__((ext_vector_type(4))) unsigned uint4v;
    uint4v pT[2][2];
#pragma unroll
    for (int qtile = 0; qtile < 2; ++qtile)
#pragma unroll
      for (int ks2 = 0; ks2 < 2; ++ks2)
#pragma unroll
        for (int jj = 0; jj < 4; ++jj) {
          int src = (jj < 2) ? shA : shB;
          unsigned vA = __shfl((int)pk[qtile][ks2 * 2][jj & 1], src, 64);
          unsigned vB = __shfl((int)pk[qtile][ks2 * 2 + 1][jj & 1], src, 64);
          pT[qtile][ks2][jj] = hiTile ? vB : vA;
        }

    // --- O^T += V^T P^T ---
#pragma unroll
    for (int ks2 = 0; ks2 < 2; ++ks2) {
      bf16x8 vf[8];
#pragma unroll
      for (int mt = 0; mt < 8; ++mt)
        vf[mt] = *(const bf16x8*)&Vc[(mt * 16 + n) * 64 + (((ks2 * 4 + quad) ^ (n & 7)) * 8)];
#pragma unroll
      for (int qtile = 0; qtile < 2; ++qtile) {
        bf16x8 pfrag = __builtin_bit_cast(bf16x8, pT[qtile][ks2]);
#pragma unroll
        for (int mt = 0; mt < 8; ++mt)
          o[qtile][mt] = __builtin_amdgcn_mfma_f32_16x16x32_bf16(vf[mt], pfrag, o[qtile][mt], 0, 0, 0);
      }
    }
  };

  stageK(0, Ks[0]); stageV(0, Vs[0]);
  for (int it = 0; it < 32; it += 2) {
    iter_body(Ks[0], Vs[0], Ks[1], Vs[1], it + 1);
    iter_body(Ks[1], Vs[1], Ks[0], Vs[0], (it + 2 < 32) ? it + 2 : -1);
  }

  // --- epilogue ---
  u16* Ybase = Y + (size_t)(b * T_ + qt * 128 + w * 32) * DIM_ + h * HD_;
#pragma unroll
  for (int qtile = 0; qtile < 2; ++qtile) {
    float inv = 1.0f / l_r[qtile];
#pragma unroll
    for (int mt = 0; mt < 8; ++mt) {
      u16x4 ov = { f2b(o[qtile][mt][0] * inv), f2b(o[qtile][mt][1] * inv),
                   f2b(o[qtile][mt][2] * inv), f2b(o[qtile][mt][3] * inv) };
      *(u16x4*)(Ybase + (size_t)(qtile * 16 + n) * DIM_ + mt * 16 + quad * 4) = ov;
    }
  }
}

extern "C" void kernel_launch(void* const* d_in, const int* in_sizes, int n_in,
                              void* d_out, int out_size, void* d_ws, size_t ws_size,
                              hipStream_t stream) {
  const float* x  = (const float*)d_in[0];
  const float* wq = (const float*)d_in[1];
  const float* wk = (const float*)d_in[2];
  const float* wv = (const float*)d_in[3];
  const float* wo = (const float*)d_in[4];

  u16* ws  = (u16*)d_ws;
  u16* xb  = ws;                   // 8388608
  u16* wqb = xb + 8388608;         // 4194304 each
  u16* wkb = wqb + 4194304;
  u16* wvb = wkb + 4194304;
  u16* wob = wvb + 4194304;
  u16* qb  = wob + 4194304;        // 8388608 each
  u16* kb  = qb + 8388608;
  u16* vb  = kb + 8388608;
  u16* vt  = vb + 8388608;
  u16* yb  = vt + 8388608;         // total 128 MiB

  cvt_bf16<<<dim3(8192, 5), 256, 0, stream>>>(x, wq, wk, wv, wo, xb, wqb, wkb, wvb, wob);
  gemm_qkv<<<dim3(16, 32, 3), 256, 0, stream>>>(xb, wqb, wkb, wvb, qb, kb, vb);
  rope_k<<<dim3(8192, 2), 256, 0, stream>>>(qb, kb);
  transpose_v<<<dim3(32, 32, 2), 256, 0, stream>>>(vb, vt);
  attn_k<<<dim3(16, 32), 256, 0, stream>>>(qb, kb, vt, yb);
  gemm_o<<<dim3(16, 32), 256, 0, stream>>>(yb, wob, (float*)d_out);
}